// Round 17
// baseline (116.211 us; speedup 1.0000x reference)
//
#include <hip/hip_runtime.h>
#include <hip/hip_bf16.h>

#define N 16384
#define D 128
#define RS 16                        // row splits (1024 rows each)
#define CT 64                        // col tiles of 256 (4 waves x 64 cols)
#define ROWS_PER_SPLIT (N / RS)      // 1024
#define ITERS (ROWS_PER_SPLIT / 32)  // 32 iterations of 32 rows

typedef __attribute__((ext_vector_type(4))) int i32x4;
typedef __attribute__((ext_vector_type(16))) int i32x16;

// ---------------- Kernel A: normalize targets -> int8 (scale 127), row-major ----------------
// For 32x32x32 i8 MFMA, lane l covers row/col (l&31) with k = ks*32 + (l>>5)*16 + j,
// j=0..15 — 16 CONTIGUOUS bytes: plain row-major i8 needs no permutation.
__global__ __launch_bounds__(256) void knorm(const float* __restrict__ t,
                                             char* __restrict__ bnq) {
    const int row  = blockIdx.x * 4 + (threadIdx.x >> 6);
    const int lane = threadIdx.x & 63;
    const float2 v = *(const float2*)(t + (size_t)row * D + lane * 2);
    float ss = v.x * v.x + v.y * v.y;
#pragma unroll
    for (int m = 1; m <= 32; m <<= 1) ss += __shfl_xor(ss, m, 64);
    const float inv = rsqrtf(ss) * 127.0f;
    char2 o;
    o.x = (char)__float2int_rn(v.x * inv);
    o.y = (char)__float2int_rn(v.y * inv);
    *(char2*)(bnq + (size_t)row * 128 + lane * 2) = o;
}

// ---------------- Kernel B: fused i8 bn @ bn^T (32x32x32) + group-argmax ----------------
// 1024 blocks x 4 waves, C=64/wave: fb[2][4]=32 + frames 32 + acc 32 ~= 112 regs
// -> fits the 128-reg budget of launch_bounds(256,4) WITHOUT spill (unlike R13,
// whose working set was 184) -> 4 waves/SIMD to interleave MFMA/VALU/load phases.
// Decode: XCD x=b&7 gets splits 2x,2x+1; co-resident blocks per CU (i stride 32,
// even) share one split -> same A-stream, L1 dedup.
__global__ __launch_bounds__(256, 4) void kargmax(const char* __restrict__ bnq,
                                                  int* __restrict__ pval,
                                                  int* __restrict__ pcode) {
    const int tid  = threadIdx.x;
    const int lane = tid & 63;
    const int w    = tid >> 6;
    const int b    = blockIdx.x;
    const int x    = b & 7;
    const int i    = b >> 3;                  // 0..127
    const int s    = x * 2 + (i & 1);         // 2 splits per XCD
    const int ct   = i >> 1;                  // 0..63
    const int j0w  = ct * 256 + w * 64;
    const int rbase = s * ROWS_PER_SPLIT;

    const int cl = lane & 31;      // row/col within 32
    const int hi = lane >> 5;      // k-half
    const int rloc = cl - 4 * hi;  // diag helper: diag when rloc == (r&3)+8*(r>>2)

    // persistent B fragments: 64 cols x 128 K, i8 (2 col-tiles x 4 K-steps, 32 VGPRs)
    i32x4 fb[2][4];
#pragma unroll
    for (int c4 = 0; c4 < 2; ++c4)
#pragma unroll
        for (int ks = 0; ks < 4; ++ks)
            fb[c4][ks] = *(const i32x4*)(bnq + (size_t)(j0w + c4 * 32 + cl) * 128 +
                                         ks * 32 + hi * 16);

    const char* aptr = bnq + (size_t)(rbase + cl) * 128 + hi * 16;

    int mv[2];
#pragma unroll
    for (int c4 = 0; c4 < 2; ++c4) mv[c4] = INT_MIN;
    int gb = hi;                       // gid = gb + 2*g; gb += 8 per iter (max 255)

    const i32x16 z16 = {0,0,0,0,0,0,0,0,0,0,0,0,0,0,0,0};
    i32x4 fA[4], fB[4];

#define LOADF(buf, itv) do {                                  \
    const char* p_ = aptr + (size_t)(itv) * 4096;             \
    buf[0] = *(const i32x4*)(p_);                             \
    buf[1] = *(const i32x4*)(p_ + 32);                        \
    buf[2] = *(const i32x4*)(p_ + 64);                        \
    buf[3] = *(const i32x4*)(p_ + 96); } while (0)

#define COMPUTEF(buf, itv) do {                                                             \
    const int r0_ = rbase + (itv) * 32;                                                     \
    const bool dg_ = ((unsigned)(r0_ - j0w) < 64u);                                         \
    i32x16 acc[2];                                                                          \
    __builtin_amdgcn_s_setprio(1);                                                          \
    _Pragma("unroll")                                                                       \
    for (int c4 = 0; c4 < 2; ++c4)                                                          \
        acc[c4] = __builtin_amdgcn_mfma_i32_32x32x32_i8(buf[0], fb[c4][0], z16, 0, 0, 0);   \
    _Pragma("unroll")                                                                       \
    for (int ks = 1; ks < 4; ++ks) {                                                        \
        _Pragma("unroll")                                                                   \
        for (int c4 = 0; c4 < 2; ++c4)                                                      \
            acc[c4] = __builtin_amdgcn_mfma_i32_32x32x32_i8(buf[ks], fb[c4][ks],            \
                                                            acc[c4], 0, 0, 0);              \
    }                                                                                       \
    __builtin_amdgcn_s_setprio(0);                                                          \
    if (dg_) {                                                                              \
        _Pragma("unroll")                                                                   \
        for (int c4 = 0; c4 < 2; ++c4)                                                      \
            if (r0_ == j0w + c4 * 32) {                                                     \
                _Pragma("unroll")                                                           \
                for (int r = 0; r < 16; ++r)                                                \
                    if (rloc == ((r & 3) + 8 * (r >> 2))) acc[c4][r] -= (1 << 30);          \
            }                                                                               \
    }                                                                                       \
    _Pragma("unroll")                                                                       \
    for (int c4 = 0; c4 < 2; ++c4) {                                                        \
        _Pragma("unroll")                                                                   \
        for (int g = 0; g < 4; ++g) {                                                       \
            const int m_ = max(max(acc[c4][4*g], acc[c4][4*g+1]),                           \
                               max(acc[c4][4*g+2], acc[c4][4*g+3]));                        \
            const int p_ = (int)(((unsigned)m_ << 8)) + (gb + 2 * g);                       \
            mv[c4] = max(mv[c4], p_);                                                       \
        }                                                                                   \
    }                                                                                       \
    gb += 8; } while (0)

    LOADF(fA, 0);
    LOADF(fB, 1);
    for (int it2 = 0; it2 < ITERS; it2 += 2) {
        COMPUTEF(fA, it2);     LOADF(fA, it2 + 2);   // overshoot -> pval pad, unused
        COMPUTEF(fB, it2 + 1); LOADF(fB, it2 + 3);
    }
#undef LOADF
#undef COMPUTEF

    // lanes l and l+32 hold different row-halves of each column: one max merges them
#pragma unroll
    for (int c4 = 0; c4 < 2; ++c4) {
        int v = mv[c4];
        v = max(v, __shfl_xor(v, 32, 64));
        if (lane < 32) {
            pval[(size_t)s * N + j0w + c4 * 32 + cl]  = v;
            pcode[(size_t)s * N + j0w + c4 * 32 + cl] = rbase + (v & 255) * 4;
        }
    }
}

// ---------------- Kernel C: merge splits, re-rank 4 candidates in fp32, hinge ----------------
__global__ __launch_bounds__(256) void kloss(const float* __restrict__ q,
                                             const float* __restrict__ t,
                                             const int* __restrict__ pval,
                                             const int* __restrict__ pcode,
                                             float* __restrict__ bsum) {
    const int j    = blockIdx.x * 4 + (threadIdx.x >> 6);
    const int lane = threadIdx.x & 63;

    // merge the RS split winners (lane s holds split s); packed ints compare directly
    int v = INT_MIN;
    int c = 0;
    if (lane < RS) { v = pval[(size_t)lane * N + j]; c = pcode[(size_t)lane * N + j]; }
#pragma unroll
    for (int m = 1; m <= 8; m <<= 1) {
        const int ov = __shfl_xor(v, m, 64);
        const int oc = __shfl_xor(c, m, 64);
        if (ov > v || (ov == v && oc < c)) { v = ov; c = oc; }
    }
    c = __shfl(c, 0, 64);

    const float2 qv = *(const float2*)(q + (size_t)j * D + lane * 2);
    const float2 tv = *(const float2*)(t + (size_t)j * D + lane * 2);
    float qq = qv.x * qv.x + qv.y * qv.y;
    float tt = tv.x * tv.x + tv.y * tv.y;
    float qt = qv.x * tv.x + qv.y * tv.y;
    float ww[4], wt[4], qw[4];
#pragma unroll
    for (int r = 0; r < 4; ++r) {
        const float2 wv = *(const float2*)(t + (size_t)(c + r) * D + lane * 2);
        ww[r] = wv.x * wv.x + wv.y * wv.y;
        wt[r] = wv.x * tv.x + wv.y * tv.y;
        qw[r] = wv.x * qv.x + wv.y * qv.y;
    }
#pragma unroll
    for (int m = 1; m <= 32; m <<= 1) {
        qq += __shfl_xor(qq, m, 64);
        tt += __shfl_xor(tt, m, 64);
        qt += __shfl_xor(qt, m, 64);
#pragma unroll
        for (int r = 0; r < 4; ++r) {
            ww[r] += __shfl_xor(ww[r], m, 64);
            wt[r] += __shfl_xor(wt[r], m, 64);
            qw[r] += __shfl_xor(qw[r], m, 64);
        }
    }
    const float pos = qt * rsqrtf(qq * tt);
    float best = -1e30f, neg = 0.f;
#pragma unroll
    for (int r = 0; r < 4; ++r) {
        float cr = wt[r] * rsqrtf(ww[r] * tt);
        if (c + r == j) cr -= 1.0f;              // diag candidate, matches sim - eye
        if (cr > best) { best = cr; neg = qw[r] * rsqrtf(qq * ww[r]); }
    }
    const float l = fmaxf(0.f, 1.0f - pos + neg);

    __shared__ float ls[4];
    if (lane == 0) ls[threadIdx.x >> 6] = l;
    __syncthreads();
    if (threadIdx.x == 0) bsum[blockIdx.x] = ls[0] + ls[1] + ls[2] + ls[3];
}

// ---------------- Kernel D: deterministic final mean ----------------
__global__ __launch_bounds__(256) void kfinal(const float* __restrict__ bsum,
                                              float* __restrict__ out) {
    float sum = 0.f;
    for (int i = threadIdx.x; i < N / 4; i += 256) sum += bsum[i];
#pragma unroll
    for (int m = 1; m <= 32; m <<= 1) sum += __shfl_xor(sum, m, 64);
    __shared__ float ws2[4];
    if ((threadIdx.x & 63) == 0) ws2[threadIdx.x >> 6] = sum;
    __syncthreads();
    if (threadIdx.x == 0) out[0] = (ws2[0] + ws2[1] + ws2[2] + ws2[3]) * (1.0f / N);
}

extern "C" void kernel_launch(void* const* d_in, const int* in_sizes, int n_in,
                              void* d_out, int out_size, void* d_ws, size_t ws_size,
                              hipStream_t stream) {
    const float* q = (const float*)d_in[0];
    const float* t = (const float*)d_in[1];
    char* ws = (char*)d_ws;

    char* bnq = ws;                                                    // 2 MB (must stay first)
    int*  pval = (int*)(ws + (size_t)N * 128);                         // 1 MB (also overshoot pad)
    int*  pcode = (int*)(ws + (size_t)N * 128 + (size_t)RS * N * 4);   // 1 MB
    float* bsum = (float*)(ws + (size_t)N * 128 + (size_t)2 * RS * N * 4); // 16 KB

    knorm<<<dim3(N / 4), dim3(256), 0, stream>>>(t, bnq);
    kargmax<<<dim3(CT * RS), dim3(256), 0, stream>>>(bnq, pval, pcode);
    kloss<<<dim3(N / 4), dim3(256), 0, stream>>>(q, t, pval, pcode, bsum);
    kfinal<<<dim3(1), dim3(256), 0, stream>>>(bsum, (float*)d_out);
}

// Round 18
// 97.597 us; speedup vs baseline: 1.1907x; 1.1907x over previous
//
#include <hip/hip_runtime.h>
#include <hip/hip_bf16.h>

#define N 16384
#define D 128
#define RS 16                        // row splits (1024 rows each)
#define CT 64                        // col tiles of 256 (4 waves x 64 cols)
#define ROWS_PER_SPLIT (N / RS)      // 1024
#define ITERS (ROWS_PER_SPLIT / 16)  // 64 iterations of 16 rows

typedef __attribute__((ext_vector_type(4))) int i32x4;

// ---------------- Kernel A: normalize targets -> int8 (scale 127), row-major ----------------
// For 16x16x64 i8 MFMA, lane l covers row (l&15), k = (l>>4)*16 + j, j=0..15 —
// 16 CONTIGUOUS bytes: plain row-major i8 IS the fragment layout.
__global__ __launch_bounds__(256) void knorm(const float* __restrict__ t,
                                             char* __restrict__ bnq) {
    const int row  = blockIdx.x * 4 + (threadIdx.x >> 6);
    const int lane = threadIdx.x & 63;
    const float2 v = *(const float2*)(t + (size_t)row * D + lane * 2);
    float ss = v.x * v.x + v.y * v.y;
#pragma unroll
    for (int m = 1; m <= 32; m <<= 1) ss += __shfl_xor(ss, m, 64);
    const float inv = rsqrtf(ss) * 127.0f;
    char2 o;
    o.x = (char)__float2int_rn(v.x * inv);
    o.y = (char)__float2int_rn(v.y * inv);
    *(char2*)(bnq + (size_t)row * 128 + lane * 2) = o;
}

// ---------------- Kernel B: fused i8 bn @ bn^T (16x16x64) + group-argmax ----------------
// 1024 blocks x 4 waves, C=64/wave, 16x16x64 i8 MFMA: working set ~85 regs
// (fb[4][2]=32, acc[4]=16 transient, frames 16) -> genuinely fits the 128-reg
// budget of launch_bounds(256,4) -> 4 waves/SIMD anti-phase MFMA/VALU overlap
// (R16 at 2 waves/SIMD: 52% combined issue; the VALU argmax depends on acc so
// a lone wave can't overlap its own phases).
// Decode: XCD x=b&7 gets splits 2x,2x+1; co-resident blocks per CU share a split.
__global__ __launch_bounds__(256, 4) void kargmax(const char* __restrict__ bnq,
                                                  int* __restrict__ pval,
                                                  int* __restrict__ pcode) {
    const int tid  = threadIdx.x;
    const int lane = tid & 63;
    const int w    = tid >> 6;
    const int b    = blockIdx.x;
    const int x    = b & 7;
    const int i    = b >> 3;                  // 0..127
    const int s    = x * 2 + (i & 1);         // 2 splits per XCD
    const int ct   = i >> 1;                  // 0..63
    const int j0w  = ct * 256 + w * 64;
    const int rbase = s * ROWS_PER_SPLIT;

    const int lr = lane & 15;      // row/col within 16
    const int lk = lane >> 4;      // k-group / row-group 0..3

    // persistent B fragments: 64 cols x 128 K, i8 (4 col-subtiles x 2 K-steps, 32 VGPRs)
    i32x4 fb[4][2];
#pragma unroll
    for (int c4 = 0; c4 < 4; ++c4)
#pragma unroll
        for (int ks = 0; ks < 2; ++ks)
            fb[c4][ks] = *(const i32x4*)(bnq + (size_t)(j0w + c4 * 16 + lr) * 128 +
                                         ks * 64 + lk * 16);

    const char* aptr = bnq + (size_t)(rbase + lr) * 128 + lk * 16;

    int mv[4];
#pragma unroll
    for (int c4 = 0; c4 < 4; ++c4) mv[c4] = INT_MIN;
    int gb = lk;                       // gid = itg*4 + lk; gb += 4 per iter (max 255)

    const i32x4 z4 = {0, 0, 0, 0};
    i32x4 fA[2], fB[2];

#define LOADF(buf, itv) do {                                  \
    const char* p_ = aptr + (size_t)(itv) * 2048;             \
    buf[0] = *(const i32x4*)(p_);                             \
    buf[1] = *(const i32x4*)(p_ + 64); } while (0)

#define COMPUTEF(buf, itv) do {                                                             \
    const int r0_ = rbase + (itv) * 16;                                                     \
    i32x4 acc[4];                                                                           \
    __builtin_amdgcn_s_setprio(1);                                                          \
    _Pragma("unroll")                                                                       \
    for (int c4 = 0; c4 < 4; ++c4)                                                          \
        acc[c4] = __builtin_amdgcn_mfma_i32_16x16x64_i8(buf[0], fb[c4][0], z4, 0, 0, 0);    \
    _Pragma("unroll")                                                                       \
    for (int c4 = 0; c4 < 4; ++c4)                                                          \
        acc[c4] = __builtin_amdgcn_mfma_i32_16x16x64_i8(buf[1], fb[c4][1], acc[c4], 0, 0, 0); \
    __builtin_amdgcn_s_setprio(0);                                                          \
    if ((unsigned)(r0_ - j0w) < 64u) {                                                      \
        _Pragma("unroll")                                                                   \
        for (int c4 = 0; c4 < 4; ++c4)                                                      \
            if (r0_ == j0w + c4 * 16) {                                                     \
                _Pragma("unroll")                                                           \
                for (int r = 0; r < 4; ++r)                                                 \
                    if (lk * 4 + r == lr) acc[c4][r] -= (1 << 30);                          \
            }                                                                               \
    }                                                                                       \
    _Pragma("unroll")                                                                       \
    for (int c4 = 0; c4 < 4; ++c4) {                                                        \
        const int m_ = max(max(acc[c4][0], acc[c4][1]), max(acc[c4][2], acc[c4][3]));       \
        mv[c4] = max(mv[c4], (int)(((unsigned)m_ << 8)) + gb);                              \
    }                                                                                       \
    gb += 4; } while (0)

    LOADF(fA, 0);
    LOADF(fB, 1);
    for (int it2 = 0; it2 < ITERS; it2 += 2) {
        COMPUTEF(fA, it2);     LOADF(fA, it2 + 2);   // overshoot -> pval pad, unused
        COMPUTEF(fB, it2 + 1); LOADF(fB, it2 + 3);
    }
#undef LOADF
#undef COMPUTEF

    // reduce across the 4 lk row-groups (lanes l, l^16, l^32, l^48 share a column)
#pragma unroll
    for (int c4 = 0; c4 < 4; ++c4) {
        int v = mv[c4];
        v = max(v, __shfl_xor(v, 16, 64));
        v = max(v, __shfl_xor(v, 32, 64));
        if (lane < 16) {
            pval[(size_t)s * N + j0w + c4 * 16 + lr]  = v;
            pcode[(size_t)s * N + j0w + c4 * 16 + lr] = rbase + (v & 255) * 4;
        }
    }
}

// ---------------- Kernel C: merge splits, re-rank 4 candidates in fp32, hinge ----------------
__global__ __launch_bounds__(256) void kloss(const float* __restrict__ q,
                                             const float* __restrict__ t,
                                             const int* __restrict__ pval,
                                             const int* __restrict__ pcode,
                                             float* __restrict__ bsum) {
    const int j    = blockIdx.x * 4 + (threadIdx.x >> 6);
    const int lane = threadIdx.x & 63;

    // merge the RS split winners (lane s holds split s); packed ints compare directly
    int v = INT_MIN;
    int c = 0;
    if (lane < RS) { v = pval[(size_t)lane * N + j]; c = pcode[(size_t)lane * N + j]; }
#pragma unroll
    for (int m = 1; m <= 8; m <<= 1) {
        const int ov = __shfl_xor(v, m, 64);
        const int oc = __shfl_xor(c, m, 64);
        if (ov > v || (ov == v && oc < c)) { v = ov; c = oc; }
    }
    c = __shfl(c, 0, 64);

    const float2 qv = *(const float2*)(q + (size_t)j * D + lane * 2);
    const float2 tv = *(const float2*)(t + (size_t)j * D + lane * 2);
    float qq = qv.x * qv.x + qv.y * qv.y;
    float tt = tv.x * tv.x + tv.y * tv.y;
    float qt = qv.x * tv.x + qv.y * tv.y;
    float ww[4], wt[4], qw[4];
#pragma unroll
    for (int r = 0; r < 4; ++r) {
        const float2 wv = *(const float2*)(t + (size_t)(c + r) * D + lane * 2);
        ww[r] = wv.x * wv.x + wv.y * wv.y;
        wt[r] = wv.x * tv.x + wv.y * tv.y;
        qw[r] = wv.x * qv.x + wv.y * qv.y;
    }
#pragma unroll
    for (int m = 1; m <= 32; m <<= 1) {
        qq += __shfl_xor(qq, m, 64);
        tt += __shfl_xor(tt, m, 64);
        qt += __shfl_xor(qt, m, 64);
#pragma unroll
        for (int r = 0; r < 4; ++r) {
            ww[r] += __shfl_xor(ww[r], m, 64);
            wt[r] += __shfl_xor(wt[r], m, 64);
            qw[r] += __shfl_xor(qw[r], m, 64);
        }
    }
    const float pos = qt * rsqrtf(qq * tt);
    float best = -1e30f, neg = 0.f;
#pragma unroll
    for (int r = 0; r < 4; ++r) {
        float cr = wt[r] * rsqrtf(ww[r] * tt);
        if (c + r == j) cr -= 1.0f;              // diag candidate, matches sim - eye
        if (cr > best) { best = cr; neg = qw[r] * rsqrtf(qq * ww[r]); }
    }
    const float l = fmaxf(0.f, 1.0f - pos + neg);

    __shared__ float ls[4];
    if (lane == 0) ls[threadIdx.x >> 6] = l;
    __syncthreads();
    if (threadIdx.x == 0) bsum[blockIdx.x] = ls[0] + ls[1] + ls[2] + ls[3];
}

// ---------------- Kernel D: deterministic final mean ----------------
__global__ __launch_bounds__(256) void kfinal(const float* __restrict__ bsum,
                                              float* __restrict__ out) {
    float sum = 0.f;
    for (int i = threadIdx.x; i < N / 4; i += 256) sum += bsum[i];
#pragma unroll
    for (int m = 1; m <= 32; m <<= 1) sum += __shfl_xor(sum, m, 64);
    __shared__ float ws2[4];
    if ((threadIdx.x & 63) == 0) ws2[threadIdx.x >> 6] = sum;
    __syncthreads();
    if (threadIdx.x == 0) out[0] = (ws2[0] + ws2[1] + ws2[2] + ws2[3]) * (1.0f / N);
}

extern "C" void kernel_launch(void* const* d_in, const int* in_sizes, int n_in,
                              void* d_out, int out_size, void* d_ws, size_t ws_size,
                              hipStream_t stream) {
    const float* q = (const float*)d_in[0];
    const float* t = (const float*)d_in[1];
    char* ws = (char*)d_ws;

    char* bnq = ws;                                                    // 2 MB (must stay first)
    int*  pval = (int*)(ws + (size_t)N * 128);                         // 1 MB (also overshoot pad)
    int*  pcode = (int*)(ws + (size_t)N * 128 + (size_t)RS * N * 4);   // 1 MB
    float* bsum = (float*)(ws + (size_t)N * 128 + (size_t)2 * RS * N * 4); // 16 KB

    knorm<<<dim3(N / 4), dim3(256), 0, stream>>>(t, bnq);
    kargmax<<<dim3(CT * RS), dim3(256), 0, stream>>>(bnq, pval, pcode);
    kloss<<<dim3(N / 4), dim3(256), 0, stream>>>(q, t, pval, pcode, bsum);
    kfinal<<<dim3(1), dim3(256), 0, stream>>>(bsum, (float*)d_out);
}

// Round 19
// 63.591 us; speedup vs baseline: 1.8275x; 1.5347x over previous
//
#include <hip/hip_runtime.h>
#include <hip/hip_bf16.h>
#include <limits.h>

#define N 16384
#define D 128
#define RS 16                        // row splits (1024 rows each)
#define CT 32                        // col tiles (N / 512)
#define ROWS_PER_SPLIT (N / RS)      // 1024
#define ITERS (ROWS_PER_SPLIT / 32)  // 32 iterations of 32 rows

typedef __attribute__((ext_vector_type(4))) int i32x4;
typedef __attribute__((ext_vector_type(16))) int i32x16;

// ---------------- Kernel A: quantize targets -> int8 + store inv-norms (t and q) ----------------
// blocks 0..4095: target rows (quantize, write invt); blocks 4096..8191: query rows (invq only).
__global__ __launch_bounds__(256) void knorm(const float* __restrict__ t,
                                             const float* __restrict__ q,
                                             char* __restrict__ bnq,
                                             float* __restrict__ invt,
                                             float* __restrict__ invq) {
    const int lane = threadIdx.x & 63;
    if (blockIdx.x < 4096) {
        const int row = blockIdx.x * 4 + (threadIdx.x >> 6);
        const float2 v = *(const float2*)(t + (size_t)row * D + lane * 2);
        float ss = v.x * v.x + v.y * v.y;
#pragma unroll
        for (int m = 1; m <= 32; m <<= 1) ss += __shfl_xor(ss, m, 64);
        const float inv = rsqrtf(ss);
        const float s127 = inv * 127.0f;
        char2 o;
        o.x = (char)__float2int_rn(v.x * s127);
        o.y = (char)__float2int_rn(v.y * s127);
        *(char2*)(bnq + (size_t)row * 128 + lane * 2) = o;
        if (lane == 0) invt[row] = inv;
    } else {
        const int row = (blockIdx.x - 4096) * 4 + (threadIdx.x >> 6);
        const float2 v = *(const float2*)(q + (size_t)row * D + lane * 2);
        float ss = v.x * v.x + v.y * v.y;
#pragma unroll
        for (int m = 1; m <= 32; m <<= 1) ss += __shfl_xor(ss, m, 64);
        if (lane == 0) invq[row] = rsqrtf(ss);
    }
}

// ---------------- Kernel B: fused i8 bn @ bn^T (32x32x32) + EXACT-row argmax ----------------
// R16 geometry (512 blocks x 4 waves, no LDS/barriers, XCD decode). int sims fit
// 21 bits -> pack (sim<<10)|local_row: argmax is exact-row, no kloss re-rank.
// Diagonal: acc set to -(1<<21) -> packed INT_MIN. C layout: col=c4*32+(lane&31),
// row(reg) = (reg&3)+8*(reg>>2)+4*(lane>>5).
__global__ __launch_bounds__(256, 2) void kargmax(const char* __restrict__ bnq,
                                                  int* __restrict__ pval,
                                                  int* __restrict__ pcode) {
    const int tid  = threadIdx.x;
    const int lane = tid & 63;
    const int w    = tid >> 6;
    const int b    = blockIdx.x;
    const int s    = (b & 7) * 2 + ((b >> 3) & 1);   // 2 splits per XCD
    const int ct   = b >> 4;                          // 0..31
    const int j0w  = ct * 512 + w * 128;
    const int rbase = s * ROWS_PER_SPLIT;

    const int cl = lane & 31;      // row/col within 32
    const int hi = lane >> 5;      // k-half
    const int rloc = cl - 4 * hi;  // diag helper: diag when rloc == (r&3)+8*(r>>2)

    // persistent B fragments: 128 cols x 128 K, i8 (4 col-tiles x 4 K-steps, 64 VGPRs)
    i32x4 fb[4][4];
#pragma unroll
    for (int c4 = 0; c4 < 4; ++c4)
#pragma unroll
        for (int ks = 0; ks < 4; ++ks)
            fb[c4][ks] = *(const i32x4*)(bnq + (size_t)(j0w + c4 * 32 + cl) * 128 +
                                         ks * 32 + hi * 16);

    const char* aptr = bnq + (size_t)(rbase + cl) * 128 + hi * 16;

    int mv[4];
#pragma unroll
    for (int c4 = 0; c4 < 4; ++c4) mv[c4] = INT_MIN;

    const i32x16 z16 = {0,0,0,0,0,0,0,0,0,0,0,0,0,0,0,0};
    i32x4 fA[4], fB[4];

#define LOADF(buf, itv) do {                                  \
    const char* p_ = aptr + (size_t)(itv) * 4096;             \
    buf[0] = *(const i32x4*)(p_);                             \
    buf[1] = *(const i32x4*)(p_ + 32);                        \
    buf[2] = *(const i32x4*)(p_ + 64);                        \
    buf[3] = *(const i32x4*)(p_ + 96); } while (0)

#define COMPUTEF(buf, itv) do {                                                             \
    const int r0_ = rbase + (itv) * 32;                                                     \
    const bool dg_ = ((unsigned)(r0_ - j0w) < 128u);                                        \
    i32x16 acc[4];                                                                          \
    __builtin_amdgcn_s_setprio(1);                                                          \
    _Pragma("unroll")                                                                       \
    for (int c4 = 0; c4 < 4; ++c4)                                                          \
        acc[c4] = __builtin_amdgcn_mfma_i32_32x32x32_i8(buf[0], fb[c4][0], z16, 0, 0, 0);   \
    _Pragma("unroll")                                                                       \
    for (int ks = 1; ks < 4; ++ks) {                                                        \
        _Pragma("unroll")                                                                   \
        for (int c4 = 0; c4 < 4; ++c4)                                                      \
            acc[c4] = __builtin_amdgcn_mfma_i32_32x32x32_i8(buf[ks], fb[c4][ks],            \
                                                            acc[c4], 0, 0, 0);              \
    }                                                                                       \
    __builtin_amdgcn_s_setprio(0);                                                          \
    if (dg_) {                                                                              \
        _Pragma("unroll")                                                                   \
        for (int c4 = 0; c4 < 4; ++c4)                                                      \
            if (r0_ == j0w + c4 * 32) {                                                     \
                _Pragma("unroll")                                                           \
                for (int r = 0; r < 16; ++r)                                                \
                    if (rloc == ((r & 3) + 8 * (r >> 2))) acc[c4][r] = -(1 << 21);          \
            }                                                                               \
    }                                                                                       \
    const int ib_ = (itv) * 32 + 4 * hi;                                                    \
    _Pragma("unroll")                                                                       \
    for (int c4 = 0; c4 < 4; ++c4) {                                                        \
        _Pragma("unroll")                                                                   \
        for (int r = 0; r < 16; ++r) {                                                      \
            const int p_ = (int)(((unsigned)acc[c4][r] << 10)) +                            \
                           (ib_ + (r & 3) + 8 * (r >> 2));                                  \
            mv[c4] = max(mv[c4], p_);                                                       \
        }                                                                                   \
    }                                                                                       \
    } while (0)

    LOADF(fA, 0);
    LOADF(fB, 1);
    for (int it2 = 0; it2 < ITERS; it2 += 2) {
        COMPUTEF(fA, it2);     LOADF(fA, it2 + 2);   // overshoot -> pval pad, unused
        COMPUTEF(fB, it2 + 1); LOADF(fB, it2 + 3);
    }
#undef LOADF
#undef COMPUTEF

    // lanes l and l+32 hold different row-halves of each column: one max merges them
#pragma unroll
    for (int c4 = 0; c4 < 4; ++c4) {
        int v = mv[c4];
        v = max(v, __shfl_xor(v, 32, 64));
        if (lane < 32) {
            pval[(size_t)s * N + j0w + c4 * 32 + cl]  = v;
            pcode[(size_t)s * N + j0w + c4 * 32 + cl] = rbase + (v & 1023);
        }
    }
}

// ---------------- Kernel C: merge splits, hinge loss with exact winner ----------------
__global__ __launch_bounds__(256) void kloss(const float* __restrict__ q,
                                             const float* __restrict__ t,
                                             const int* __restrict__ pval,
                                             const int* __restrict__ pcode,
                                             const float* __restrict__ invt,
                                             const float* __restrict__ invq,
                                             float* __restrict__ bsum) {
    const int j    = blockIdx.x * 4 + (threadIdx.x >> 6);
    const int lane = threadIdx.x & 63;

    // merge the RS split winners (lane s holds split s)
    int v = INT_MIN;
    int c = 0;
    if (lane < RS) { v = pval[(size_t)lane * N + j]; c = pcode[(size_t)lane * N + j]; }
#pragma unroll
    for (int m = 1; m <= 8; m <<= 1) {
        const int ov = __shfl_xor(v, m, 64);
        const int oc = __shfl_xor(c, m, 64);
        if (ov > v || (ov == v && oc < c)) { v = ov; c = oc; }
    }
    c = __shfl(c, 0, 64);

    const float2 qv = *(const float2*)(q + (size_t)j * D + lane * 2);
    const float2 tv = *(const float2*)(t + (size_t)j * D + lane * 2);
    const float2 wv = *(const float2*)(t + (size_t)c * D + lane * 2);
    float qt = qv.x * tv.x + qv.y * tv.y;
    float qw = qv.x * wv.x + qv.y * wv.y;
#pragma unroll
    for (int m = 1; m <= 32; m <<= 1) {
        qt += __shfl_xor(qt, m, 64);
        qw += __shfl_xor(qw, m, 64);
    }
    const float iq = invq[j];
    const float pos = qt * iq * invt[j];
    const float neg = qw * iq * invt[c];
    const float l = fmaxf(0.f, 1.0f - pos + neg);

    __shared__ float ls[4];
    if (lane == 0) ls[threadIdx.x >> 6] = l;
    __syncthreads();
    if (threadIdx.x == 0) bsum[blockIdx.x] = ls[0] + ls[1] + ls[2] + ls[3];
}

// ---------------- Kernel D: deterministic final mean ----------------
__global__ __launch_bounds__(256) void kfinal(const float* __restrict__ bsum,
                                              float* __restrict__ out) {
    float sum = 0.f;
    for (int i = threadIdx.x; i < N / 4; i += 256) sum += bsum[i];
#pragma unroll
    for (int m = 1; m <= 32; m <<= 1) sum += __shfl_xor(sum, m, 64);
    __shared__ float ws2[4];
    if ((threadIdx.x & 63) == 0) ws2[threadIdx.x >> 6] = sum;
    __syncthreads();
    if (threadIdx.x == 0) out[0] = (ws2[0] + ws2[1] + ws2[2] + ws2[3]) * (1.0f / N);
}

extern "C" void kernel_launch(void* const* d_in, const int* in_sizes, int n_in,
                              void* d_out, int out_size, void* d_ws, size_t ws_size,
                              hipStream_t stream) {
    const float* q = (const float*)d_in[0];
    const float* t = (const float*)d_in[1];
    char* ws = (char*)d_ws;

    char* bnq = ws;                                                    // 2 MB (must stay first)
    int*  pval = (int*)(ws + (size_t)N * 128);                         // 1 MB (also overshoot pad)
    int*  pcode = (int*)(ws + (size_t)N * 128 + (size_t)RS * N * 4);   // 1 MB
    float* invt = (float*)(ws + (size_t)N * 128 + (size_t)2 * RS * N * 4);      // 64 KB
    float* invq = invt + N;                                            // 64 KB
    float* bsum = invq + N;                                            // 16 KB

    knorm<<<dim3(N / 2), dim3(256), 0, stream>>>(t, q, bnq, invt, invq);
    kargmax<<<dim3(CT * RS), dim3(256), 0, stream>>>(bnq, pval, pcode);
    kloss<<<dim3(N / 4), dim3(256), 0, stream>>>(q, t, pval, pcode, invt, invq, bsum);
    kfinal<<<dim3(1), dim3(256), 0, stream>>>(bsum, (float*)d_out);
}